// Round 8
// baseline (434.936 us; speedup 1.0000x reference)
//
#include <hip/hip_runtime.h>

// OccurrencePool R10b (de-risked resubmit; two consecutive container
// failures with __launch_bounds__(512,4) — the min-waves/EU constraint is
// the only structural difference from proven kernels, so it is dropped;
// LDS=64KB already pins occupancy at 2 blocks/CU).
// = R9 (376us) + TLP doubling in the MFMA kernels:
//  - k_occ / k_feat: 256 -> 512 threads (8 waves/block). Same 64KB double
//    buffer, same counted-vmcnt rounds, half the per-wave work -> 16
//    waves/CU (4/SIMD) instead of 8 for latency hiding in staging rounds.
//  - k_transpose: weight-convert spread over ALL 4096 blocks.
//  - k_out: R9 LDS-staged version unchanged.
//   r1  = relu(W1 x + b1)                          (bf16 MFMA, 34.4 GF)
//   occ = |W3 relu(W2o relu(W1o x + b1o) + b2o)|   (bf16 MFMA, 10.2 GF)
//   M[b,o,j]   = sum_s occ[b,o,s] r1[b,j,s]        (bf16 MFMA, 4.3 GF)
//   out[b,o,c] = (sum_j M[o,j] W2[c,j] + b2[c]*sumocc[b,o]) / S
// Tile layout (per 128-voxel tile, per 64-wide K chunk kc):
//   linear = kc*8192 + k8*1024 + row*8 + k0   (shorts; k8=(k>>3)&7, k0=k&7)

#define S_TOT 16384  // T*H*W per batch

typedef __attribute__((ext_vector_type(8))) short bf8_t;  // 8 bf16 (4 VGPRs)
typedef __attribute__((ext_vector_type(4))) short s4_t;   // 4 bf16
typedef __attribute__((ext_vector_type(4))) float f4_t;

#define MFMA __builtin_amdgcn_mfma_f32_16x16x32_bf16

#define BAR_FENCE() do { __builtin_amdgcn_s_barrier(); \
                         asm volatile("" ::: "memory"); } while (0)
#define WAIT_VM4()  asm volatile("s_waitcnt vmcnt(4)" ::: "memory")
#define WAIT_VM0()  asm volatile("s_waitcnt vmcnt(0)" ::: "memory")
#define WAIT_LGKM0() asm volatile("s_waitcnt lgkmcnt(0)" ::: "memory")

__device__ __forceinline__ short f2bf(float f) {
  union { float f; unsigned u; } v; v.f = f;
  unsigned u = v.u + 0x7FFFu + ((v.u >> 16) & 1u);  // RNE
  return (short)(u >> 16);
}

__device__ __forceinline__ void glds16(const void* g, void* l) {
  __builtin_amdgcn_global_load_lds(
      (const __attribute__((address_space(1))) void*)g,
      (__attribute__((address_space(3))) void*)l, 16, 0, 0);
}

// Contiguous 16KB global -> LDS copy for 8 waves: 2 glds/wave, each
// lane-contiguous 1KB: g + off + lane*8 shorts; HW adds lane*16B on LDS side.
__device__ __forceinline__ void stage16k8(const short* g, short* lds,
                                          int wv, int lane) {
#pragma unroll
  for (int i = 0; i < 2; ++i) {
    const int off = (wv * 2 + i) * 512;
    glds16(g + off + lane * 8, lds + off);
  }
}

// ------ x transpose + weight convert (spread over all blocks) ---------------
__global__ __launch_bounds__(256) void k_transpose(
    const float* __restrict__ x, short* __restrict__ xTs,
    const float* __restrict__ w1, const float* __restrict__ wo1,
    const float* __restrict__ wo2, const float* __restrict__ wo3,
    short* __restrict__ wb) {
  __shared__ float tls[64][129];  // [c(64)][s(128)+pad]
  const int sb = blockIdx.x, cb = blockIdx.y, b = blockIdx.z;  // sb = st
  const int t = threadIdx.x;
  {  // weight convert: 4096 blocks x 256 thr = 1M slots >= 339968 elems
    const int bid = (b * 8 + cb) * 128 + sb;
    const int i = bid * 256 + t;
    if (i < 339968) {
      if (i < 262144) {  // w1[j][k] -> [jc][kc][k8][j&127][k0]
        const int j = i >> 9, k = i & 511;
        const int di = ((j >> 7) * 8 + (k >> 6)) * 8192 +
                       ((k >> 3) & 7) * 1024 + (j & 127) * 8 + (k & 7);
        wb[di] = f2bf(w1[i]);
      } else if (i < 327680) {  // wo1[c4][k] -> [kc][k8][c4][k0]
        const int e = i - 262144;
        const int c4 = e >> 9, k = e & 511;
        const int di = 262144 + (k >> 6) * 8192 + ((k >> 3) & 7) * 1024 +
                       c4 * 8 + (k & 7);
        wb[di] = f2bf(wo1[e]);
      } else if (i < 335872) {
        wb[i] = f2bf(wo2[i - 327680]);
      } else {
        wb[i] = f2bf(wo3[i - 335872]);
      }
    }
  }
  {
    const int cr = t >> 2, ss = (t & 3) * 32;  // 128B-contiguous per thread
    const float* src = x + ((size_t)b * 512 + cb * 64 + cr) * S_TOT +
                       sb * 128 + ss;
#pragma unroll
    for (int k = 0; k < 8; ++k) {
      f4_t v = *(const f4_t*)(src + k * 4);
#pragma unroll
      for (int j = 0; j < 4; ++j) tls[cr][ss + k * 4 + j] = v[j];
    }
  }
  __syncthreads();
  {
#pragma unroll
    for (int h = 0; h < 2; ++h) {  // 512 items = 2 per thread
      const int id = h * 256 + t;
      const int s_in = id >> 2, cs = (id & 3) * 16, k8 = cs >> 3;
      alignas(16) short tmp[16];
#pragma unroll
      for (int j = 0; j < 16; ++j) tmp[j] = f2bf(tls[cs + j][s_in]);
      short* base = xTs + (((size_t)(b * 128 + sb) * 8 + cb) * 8 + k8) * 1024 +
                    s_in * 8;
      *(bf8_t*)base          = *(const bf8_t*)&tmp[0];
      *(bf8_t*)(base + 1024) = *(const bf8_t*)&tmp[8];
    }
  }
}

// ---------------- occ chain: 3 fused GEMMs per 128-voxel tile ---------------
// 8 waves. K-loop: counted-vmcnt pipeline. Phase1 waves tile [c4]x[s] 2x4;
// phases 2/3 split s only (16 cols/wave) so h2s stays wave-private.
__global__ __launch_bounds__(512) void k_occ(
    const short* __restrict__ xTs, const short* __restrict__ wo1,
    const short* __restrict__ wo2, const short* __restrict__ wo3,
    const float* __restrict__ bo1, const float* __restrict__ bo2,
    short* __restrict__ occP, float* __restrict__ sumocc) {
  __shared__ short smem[32768];  // 64KB: buf0 | buf1 (32KB each)
  short* const buf0 = smem;
  short* const buf1 = smem + 16384;
  short* const h1s = buf0;   // 32KB planar [c4chunk][s] after K-loop
  short* const h2s = buf1;   // 16KB planar [c8chunk][s]
  const int tile = blockIdx.x, b = blockIdx.y;
  const int t = threadIdx.x, lane = t & 63, wv = t >> 6;  // wv 0..7
  const int q = lane >> 4, li = lane & 15;
  const int mh1 = (wv & 1) * 64;   // c4-row half for phase 1
  const int nhs = (wv >> 1) * 32;  // s-col 32-strip for phase 1
  const int swc = wv * 16;         // s-col 16-strip for phases 2/3
  const short* xTb = xTs + (size_t)(b * 128 + tile) * 65536;
  const f4_t fz = {0.f, 0.f, 0.f, 0.f};

  // phase 1: h1 = relu(Wo1 @ x + b1o)  [c4=128 x s=128], K=512, pipelined
  f4_t hcc[4][2];
#pragma unroll
  for (int i = 0; i < 4; ++i) { hcc[i][0] = fz; hcc[i][1] = fz; }

  stage16k8(xTb, buf1, wv, lane);          // chunk0 -> buf1
  stage16k8(wo1, buf1 + 8192, wv, lane);
  for (int i = 0; i < 8; ++i) {
    BAR_FENCE();  // A: prev chunk's buffer reads retired by all waves
    if (i < 7) {
      short* nb_ = (i & 1) ? buf1 : buf0;
      stage16k8(xTb + (i + 1) * 8192, nb_, wv, lane);
      stage16k8(wo1 + (i + 1) * 8192, nb_ + 8192, wv, lane);
      WAIT_VM4();  // my chunk-i 4 glds landed; chunk-i+1's stay in flight
    } else {
      WAIT_VM0();
    }
    BAR_FENCE();  // B: everyone's chunk-i staged data visible
    const short* xs = (i & 1) ? buf0 : buf1;
    const short* wsp = xs + 8192;
#pragma unroll
    for (int kk = 0; kk < 2; ++kk) {
      const int pl = (4 * kk + q) * 128;
      bf8_t a[4], bb[2];
#pragma unroll
      for (int ma = 0; ma < 4; ++ma)
        a[ma] = *(const bf8_t*)&wsp[(pl + mh1 + 16 * ma + li) * 8];
#pragma unroll
      for (int nb = 0; nb < 2; ++nb)
        bb[nb] = *(const bf8_t*)&xs[(pl + nhs + 16 * nb + li) * 8];
#pragma unroll
      for (int ma = 0; ma < 4; ++ma)
#pragma unroll
        for (int nb = 0; nb < 2; ++nb)
          hcc[ma][nb] = MFMA(a[ma], bb[nb], hcc[ma][nb], 0, 0, 0);
    }
  }
  WAIT_LGKM0();
  BAR_FENCE();  // chunk7 (buf0) reads retired everywhere; buf0 reusable
  // bias+relu -> h1s planar [c4chunk][s]
#pragma unroll
  for (int ma = 0; ma < 4; ++ma) {
    const int c40 = mh1 + 16 * ma + 4 * q;
    f4_t bv = *(const f4_t*)(bo1 + c40);
#pragma unroll
    for (int nb = 0; nb < 2; ++nb) {
      const int sl = nhs + 16 * nb + li;
      s4_t p;
#pragma unroll
      for (int r = 0; r < 4; ++r) p[r] = f2bf(fmaxf(hcc[ma][nb][r] + bv[r], 0.0f));
      *(s4_t*)&h1s[((c40 >> 3) * 128 + sl) * 8 + (c40 & 7)] = p;
    }
  }
  __syncthreads();
  // phase 2: h2 = relu(Wo2 @ h1 + b2o)  [c8=64 x s=16/wave], K=c4=128
  f4_t a2[4];
#pragma unroll
  for (int i = 0; i < 4; ++i) a2[i] = fz;
#pragma unroll
  for (int kk = 0; kk < 4; ++kk) {
    const int pl = (4 * kk + q) * 128;
    bf8_t a[4], bb;
#pragma unroll
    for (int ma = 0; ma < 4; ++ma)
      a[ma] = *(const bf8_t*)(wo2 + (size_t)(16 * ma + li) * 128 + kk * 32 + q * 8);
    bb = *(const bf8_t*)&h1s[(pl + swc + li) * 8];
#pragma unroll
    for (int ma = 0; ma < 4; ++ma)
      a2[ma] = MFMA(a[ma], bb, a2[ma], 0, 0, 0);
  }
  // h2 -> h2s planar [c8chunk][s]; wave-private s cols (no barrier)
#pragma unroll
  for (int ma = 0; ma < 4; ++ma) {
    const int c80 = 16 * ma + 4 * q;
    f4_t bv = *(const f4_t*)(bo2 + c80);
    const int sl = swc + li;
    s4_t p;
#pragma unroll
    for (int r = 0; r < 4; ++r) p[r] = f2bf(fmaxf(a2[ma][r] + bv[r], 0.0f));
    *(s4_t*)&h2s[((c80 >> 3) * 128 + sl) * 8 + (c80 & 7)] = p;
  }
  // phase 3: occ = |Wo3 @ h2|  [o=64 x s=16/wave], K=c8=64
  f4_t a3[4];
#pragma unroll
  for (int i = 0; i < 4; ++i) a3[i] = fz;
#pragma unroll
  for (int kk = 0; kk < 2; ++kk) {
    const int pl = (4 * kk + q) * 128;
    bf8_t a[4], bb;
#pragma unroll
    for (int ma = 0; ma < 4; ++ma)
      a[ma] = *(const bf8_t*)(wo3 + (size_t)(16 * ma + li) * 64 + kk * 32 + q * 8);
    bb = *(const bf8_t*)&h2s[(pl + swc + li) * 8];
#pragma unroll
    for (int ma = 0; ma < 4; ++ma)
      a3[ma] = MFMA(a[ma], bb, a3[ma], 0, 0, 0);
  }
  // |.| -> occP planar tile [s8][o][s0]
  short* ot = occP + (size_t)(b * 128 + tile) * 8192;
#pragma unroll
  for (int ma = 0; ma < 4; ++ma) {
    const int o = 16 * ma + 4 * q;
    const int sl = swc + li;
#pragma unroll
    for (int r = 0; r < 4; ++r)
      ot[(sl >> 3) * 512 + (o + r) * 8 + (sl & 7)] = f2bf(fabsf(a3[ma][r]));
  }
  // sumocc[b][o] += sum_s |occ| (fp32); each wave covers 16 s-cols
#pragma unroll
  for (int ma = 0; ma < 4; ++ma)
#pragma unroll
    for (int r = 0; r < 4; ++r) {
      float v = fabsf(a3[ma][r]);
#pragma unroll
      for (int m = 1; m < 16; m <<= 1) v += __shfl_xor(v, m, 64);
      if (li == 0) atomicAdd(&sumocc[b * 64 + 16 * ma + 4 * q + r], v);
    }
}

// ---------------- r1 GEMM + spatial contraction into M ----------------------
// 8 waves: r1 [s]x[j] tiled 2x4; contraction splits j (16 cols/wave).
__global__ __launch_bounds__(512) void k_feat(
    const short* __restrict__ xTs, const short* __restrict__ w1s,
    const float* __restrict__ b1, const short* __restrict__ occP,
    float* __restrict__ M) {
  __shared__ short smem[32768];  // 64KB: buf0 | buf1
  short* const buf0 = smem;
  short* const buf1 = smem + 16384;
  short* const r1s = buf0;  // 32KB planar [schunk][j] after each K-loop
  const int sg = blockIdx.x, cb = blockIdx.y, b = blockIdx.z;
  const int t = threadIdx.x, lane = t & 63, wv = t >> 6;  // wv 0..7
  const int q = lane >> 4, li = lane & 15;
  const int mh1 = (wv & 1) * 64;   // s-row half
  const int nhs = (wv >> 1) * 32;  // j-col 32-strip
  const int jwc = wv * 16;         // j-col 16-strip (contraction)
  const short* w1b = w1s + (size_t)cb * 65536;  // [kc][k8][j][k0] for this jc
  const f4_t fz = {0.f, 0.f, 0.f, 0.f};

  float biasv[2];
  biasv[0] = b1[cb * 128 + nhs + li];
  biasv[1] = b1[cb * 128 + nhs + 16 + li];

  f4_t macc[4];
#pragma unroll
  for (int i = 0; i < 4; ++i) macc[i] = fz;

  // prologue: tile0 chunk0 -> buf1
  {
    const short* xT0 = xTs + (size_t)(b * 128 + sg * 4) * 65536;
    stage16k8(xT0, buf1, wv, lane);
    stage16k8(w1b, buf1 + 8192, wv, lane);
  }

  for (int tt = 0; tt < 4; ++tt) {
    const int st = sg * 4 + tt;
    const short* xTb = xTs + (size_t)(b * 128 + st) * 65536;
    f4_t acc[4][2];
#pragma unroll
    for (int i = 0; i < 4; ++i) { acc[i][0] = fz; acc[i][1] = fz; }

    for (int i = 0; i < 8; ++i) {
      BAR_FENCE();  // A: prev chunk's (and prev contraction's) LDS reads done
      if (i < 7) {
        short* nb_ = (i & 1) ? buf1 : buf0;
        stage16k8(xTb + (i + 1) * 8192, nb_, wv, lane);
        stage16k8(w1b + (i + 1) * 8192, nb_ + 8192, wv, lane);
        WAIT_VM4();  // chunk-i landed; chunk-i+1 stays in flight
      } else {
        WAIT_VM0();
      }
      BAR_FENCE();  // B: all waves' chunk-i visible
      const short* xs = (i & 1) ? buf0 : buf1;
      const short* wsp = xs + 8192;
#pragma unroll
      for (int kk = 0; kk < 2; ++kk) {
        const int pl = (4 * kk + q) * 128;
        bf8_t a[4], bb[2];
#pragma unroll
        for (int ma = 0; ma < 4; ++ma)
          a[ma] = *(const bf8_t*)&xs[(pl + mh1 + 16 * ma + li) * 8];
#pragma unroll
        for (int nb = 0; nb < 2; ++nb)
          bb[nb] = *(const bf8_t*)&wsp[(pl + nhs + 16 * nb + li) * 8];
#pragma unroll
        for (int ma = 0; ma < 4; ++ma)
#pragma unroll
          for (int nb = 0; nb < 2; ++nb)
            acc[ma][nb] = MFMA(a[ma], bb[nb], acc[ma][nb], 0, 0, 0);
      }
    }
    WAIT_LGKM0();
    BAR_FENCE();  // chunk7 (buf0) reads retired everywhere; buf0 reusable
    // r1 = relu(acc + b1) -> r1s planar [schunk][j] (buf0)
#pragma unroll
    for (int ma = 0; ma < 4; ++ma) {
      const int sl0 = mh1 + 16 * ma + 4 * q;  // 4 consecutive s
#pragma unroll
      for (int nb = 0; nb < 2; ++nb) {
        const int jl = nhs + 16 * nb + li;
        s4_t p;
#pragma unroll
        for (int r = 0; r < 4; ++r)
          p[r] = f2bf(fmaxf(acc[ma][nb][r] + biasv[nb], 0.0f));
        *(s4_t*)&r1s[((sl0 >> 3) * 128 + jl) * 8 + (sl0 & 7)] = p;
      }
    }
    WAIT_LGKM0();
    BAR_FENCE();  // r1s visible to all waves
    // occ A-frags from global FIRST (older than prologue glds)
    const short* ot = occP + (size_t)(b * 128 + st) * 8192;
    bf8_t af[4][4];
#pragma unroll
    for (int kc = 0; kc < 4; ++kc)
#pragma unroll
      for (int ma = 0; ma < 4; ++ma)
        af[kc][ma] = *(const bf8_t*)(ot + ((kc * 4 + q) * 64 + 16 * ma + li) * 8);
    // next tile's chunk0 prologue -> buf1 (chunk6 reads retired at i=7 A)
    if (tt < 3) {
      stage16k8(xTb + 65536, buf1, wv, lane);
      stage16k8(w1b, buf1 + 8192, wv, lane);
    }
    // M[o][j] += occ[o][s] * r1[j][s]  (K = s = 128); 16 j-cols per wave
#pragma unroll
    for (int kc = 0; kc < 4; ++kc) {
      const int pl = (4 * kc + q) * 128;
      bf8_t bb = *(const bf8_t*)&r1s[(pl + jwc + li) * 8];
#pragma unroll
      for (int ma = 0; ma < 4; ++ma)
        macc[ma] = MFMA(af[kc][ma], bb, macc[ma], 0, 0, 0);
    }
  }
  // flush partial M (64 o x 16 j per wave) once
#pragma unroll
  for (int ma = 0; ma < 4; ++ma) {
    const int jg = cb * 128 + jwc + li;
#pragma unroll
    for (int r = 0; r < 4; ++r) {
      const int o = 16 * ma + 4 * q + r;
      atomicAdd(&M[((size_t)b * 64 + o) * 512 + jg], macc[ma][r]);
    }
  }
}

// ---------------- epilogue: out = (M @ W2^T + sumocc * b2^T) / S ------------
__global__ __launch_bounds__(256) void k_out(
    const float* __restrict__ M, const float* __restrict__ sumocc,
    const float* __restrict__ w2, const float* __restrict__ b2,
    float* __restrict__ out) {
  __shared__ float Mlds[16][516];
  __shared__ float Wlds[16][516];
  const int cg = blockIdx.x, og = blockIdx.y, b = blockIdx.z;
  const int t = threadIdx.x;
  const float* Msrc = M + ((size_t)b * 64 + og * 16) * 512;
  const float* Wsrc = w2 + (size_t)cg * 16 * 512;
#pragma unroll
  for (int k = 0; k < 8; ++k) {
    const int fi = k * 256 + t;              // f4 index 0..2047
    const int row = fi >> 7, col = (fi & 127) * 4;
    *(f4_t*)&Mlds[row][col] = *(const f4_t*)(Msrc + row * 512 + col);
    *(f4_t*)&Wlds[row][col] = *(const f4_t*)(Wsrc + row * 512 + col);
  }
  __syncthreads();
  const int o = t >> 4, c = t & 15;
  float s0 = 0.f, s1 = 0.f;
#pragma unroll 8
  for (int j = 0; j < 512; j += 8) {
    f4_t m0 = *(const f4_t*)&Mlds[o][j];
    f4_t w0 = *(const f4_t*)&Wlds[c][j];
    f4_t m1 = *(const f4_t*)&Mlds[o][j + 4];
    f4_t w1 = *(const f4_t*)&Wlds[c][j + 4];
    s0 += m0[0] * w0[0] + m0[1] * w0[1] + m0[2] * w0[2] + m0[3] * w0[3];
    s1 += m1[0] * w1[0] + m1[1] * w1[1] + m1[2] * w1[2] + m1[3] * w1[3];
  }
  const int og_ = og * 16 + o, cg_ = cg * 16 + c;
  out[((size_t)b * 64 + og_) * 512 + cg_] =
      ((s0 + s1) + sumocc[b * 64 + og_] * b2[cg_]) * (1.0f / 16384.0f);
}

// ---------------- launch ----------------------------------------------------
// ws layout (bytes):
//   0         xTs     4*16384*512 bf16 = 67108864   (swizzled tiles)
//   67108864  wb      339968 bf16 (w1s | wo1s | wo2 | wo3) = 679936
//   67788800  occP    4*64*16384 bf16  = 8388608    (planar tiles)
//   76177408  M       4*64*512 fp32    = 524288
//   76701696  sumocc  256 fp32         = 1024
extern "C" void kernel_launch(void* const* d_in, const int* in_sizes, int n_in,
                              void* d_out, int out_size, void* d_ws, size_t ws_size,
                              hipStream_t stream) {
  (void)in_sizes; (void)n_in; (void)out_size; (void)ws_size;
  const float* x      = (const float*)d_in[0];
  const float* w_add1 = (const float*)d_in[1];
  const float* b_add1 = (const float*)d_in[2];
  const float* w_add2 = (const float*)d_in[3];
  const float* b_add2 = (const float*)d_in[4];
  const float* w_occ1 = (const float*)d_in[5];
  const float* b_occ1 = (const float*)d_in[6];
  const float* w_occ2 = (const float*)d_in[7];
  const float* b_occ2 = (const float*)d_in[8];
  const float* w_occ3 = (const float*)d_in[9];

  char* ws = (char*)d_ws;
  short* xTs     = (short*)(ws);
  short* wb      = (short*)(ws + 67108864);
  short* occP    = (short*)(ws + 67788800);
  float* M       = (float*)(ws + 76177408);
  float* sumocc  = (float*)(ws + 76701696);

  hipMemsetAsync(M, 0, 524288 + 1024, stream);  // M + sumocc
  k_transpose<<<dim3(128, 8, 4), dim3(256), 0, stream>>>(
      x, xTs, w_add1, w_occ1, w_occ2, w_occ3, wb);

  const short* w1sp = wb;
  const short* wbo1 = wb + 262144;
  const short* wbo2 = wb + 327680;
  const short* wbo3 = wb + 335872;
  k_occ<<<dim3(128, 4), dim3(512), 0, stream>>>(xTs, wbo1, wbo2, wbo3,
                                                b_occ1, b_occ2, occP, sumocc);
  k_feat<<<dim3(32, 4, 4), dim3(512), 0, stream>>>(xTs, w1sp, b_add1, occP, M);
  k_out<<<dim3(32, 4, 4), dim3(256), 0, stream>>>(M, sumocc, w_add2, b_add2,
                                                  (float*)d_out);
}

// Round 9
// 382.843 us; speedup vs baseline: 1.1361x; 1.1361x over previous
//
#include <hip/hip_runtime.h>

// OccurrencePool R11 = R9 (best, 376us) with HYBRID operand sourcing:
// stage only the per-block-UNIQUE x chunks into LDS (16KB/round, counted
// vmcnt); load the SHARED weight fragments (wo1/w1, pre-swizzled so frags
// are lane-contiguous 16B) directly from L2-hot global inside the MFMA
// phase. Rationale: R6 proved direct-global x overfetches 10x (unique data
// thrashes L2) but weights are 128KB, read by all 512 blocks -> L2
// broadcast hits. R9 staged wo1 per block = 64MB redundant traffic and
// doubled every round's payload. R10b proved 512-thr TLP hurts (94->165us);
// 256 thr kept. k_occ LDS 64->48KB (3 blocks/CU); k_feat r1s de-aliased.
//   r1  = relu(W1 x + b1)                          (bf16 MFMA, 34.4 GF)
//   occ = |W3 relu(W2o relu(W1o x + b1o) + b2o)|   (bf16 MFMA, 10.2 GF)
//   M[b,o,j]   = sum_s occ[b,o,s] r1[b,j,s]        (bf16 MFMA, 4.3 GF)
//   out[b,o,c] = (sum_j M[o,j] W2[c,j] + b2[c]*sumocc[b,o]) / S
// Tile layout (per 128-voxel tile, per 64-wide K chunk kc):
//   linear = kc*8192 + k8*1024 + row*8 + k0   (shorts; k8=(k>>3)&7, k0=k&7)

#define S_TOT 16384  // T*H*W per batch

typedef __attribute__((ext_vector_type(8))) short bf8_t;  // 8 bf16 (4 VGPRs)
typedef __attribute__((ext_vector_type(4))) short s4_t;   // 4 bf16
typedef __attribute__((ext_vector_type(4))) float f4_t;

#define MFMA __builtin_amdgcn_mfma_f32_16x16x32_bf16

// raw barrier + code-motion fence (prevent LDS reads hoisting above barrier)
#define BAR_FENCE() do { __builtin_amdgcn_s_barrier(); \
                         asm volatile("" ::: "memory"); } while (0)
#define WAIT_VM4()  asm volatile("s_waitcnt vmcnt(4)" ::: "memory")
#define WAIT_VM0()  asm volatile("s_waitcnt vmcnt(0)" ::: "memory")
#define WAIT_LGKM0() asm volatile("s_waitcnt lgkmcnt(0)" ::: "memory")

__device__ __forceinline__ short f2bf(float f) {
  union { float f; unsigned u; } v; v.f = f;
  unsigned u = v.u + 0x7FFFu + ((v.u >> 16) & 1u);  // RNE
  return (short)(u >> 16);
}

__device__ __forceinline__ void glds16(const void* g, void* l) {
  __builtin_amdgcn_global_load_lds(
      (const __attribute__((address_space(1))) void*)g,
      (__attribute__((address_space(3))) void*)l, 16, 0, 0);
}

// Contiguous 16KB global -> LDS copy (4 waves): 4 glds/wave, each
// lane-contiguous 1KB: g + off + lane*8 shorts; HW adds lane*16B on LDS side.
__device__ __forceinline__ void stage16k(const short* g, short* lds,
                                         int wv, int lane) {
#pragma unroll
  for (int i = 0; i < 4; ++i) {
    const int off = (wv * 4 + i) * 512;
    glds16(g + off + lane * 8, lds + off);
  }
}

// ------ x transpose + weight convert (spread over all blocks) ---------------
__global__ __launch_bounds__(256) void k_transpose(
    const float* __restrict__ x, short* __restrict__ xTs,
    const float* __restrict__ w1, const float* __restrict__ wo1,
    const float* __restrict__ wo2, const float* __restrict__ wo3,
    short* __restrict__ wb) {
  __shared__ float tls[64][129];  // [c(64)][s(128)+pad]
  const int sb = blockIdx.x, cb = blockIdx.y, b = blockIdx.z;  // sb = st
  const int t = threadIdx.x;
  {  // weight convert: 4096 blocks x 256 thr = 1M slots >= 339968 elems
    const int bid = (b * 8 + cb) * 128 + sb;
    const int i = bid * 256 + t;
    if (i < 339968) {
      if (i < 262144) {  // w1[j][k] -> [jc][kc][k8][j&127][k0]
        const int j = i >> 9, k = i & 511;
        const int di = ((j >> 7) * 8 + (k >> 6)) * 8192 +
                       ((k >> 3) & 7) * 1024 + (j & 127) * 8 + (k & 7);
        wb[di] = f2bf(w1[i]);
      } else if (i < 327680) {  // wo1[c4][k] -> [kc][k8][c4][k0]
        const int e = i - 262144;
        const int c4 = e >> 9, k = e & 511;
        const int di = 262144 + (k >> 6) * 8192 + ((k >> 3) & 7) * 1024 +
                       c4 * 8 + (k & 7);
        wb[di] = f2bf(wo1[e]);
      } else if (i < 335872) {
        wb[i] = f2bf(wo2[i - 327680]);
      } else {
        wb[i] = f2bf(wo3[i - 335872]);
      }
    }
  }
  {
    const int cr = t >> 2, ss = (t & 3) * 32;  // 128B-contiguous per thread
    const float* src = x + ((size_t)b * 512 + cb * 64 + cr) * S_TOT +
                       sb * 128 + ss;
#pragma unroll
    for (int k = 0; k < 8; ++k) {
      f4_t v = *(const f4_t*)(src + k * 4);
#pragma unroll
      for (int j = 0; j < 4; ++j) tls[cr][ss + k * 4 + j] = v[j];
    }
  }
  __syncthreads();
  {
#pragma unroll
    for (int h = 0; h < 2; ++h) {  // 512 items = 2 per thread
      const int id = h * 256 + t;
      const int s_in = id >> 2, cs = (id & 3) * 16, k8 = cs >> 3;
      alignas(16) short tmp[16];
#pragma unroll
      for (int j = 0; j < 16; ++j) tmp[j] = f2bf(tls[cs + j][s_in]);
      short* base = xTs + (((size_t)(b * 128 + sb) * 8 + cb) * 8 + k8) * 1024 +
                    s_in * 8;
      *(bf8_t*)base          = *(const bf8_t*)&tmp[0];
      *(bf8_t*)(base + 1024) = *(const bf8_t*)&tmp[8];
    }
  }
}

// ---------------- occ chain: 3 fused GEMMs per 128-voxel tile ---------------
// 4 waves, 48KB LDS (3 blocks/CU). K-loop stages x only (16KB/round,
// counted vmcnt); wo1 A-frags direct from L2-hot global.
// occP output layout per tile: [s8(16)][o(64)][s0(8)] = planar A-operand image
__global__ __launch_bounds__(256) void k_occ(
    const short* __restrict__ xTs, const short* __restrict__ wo1,
    const short* __restrict__ wo2, const short* __restrict__ wo3,
    const float* __restrict__ bo1, const float* __restrict__ bo2,
    short* __restrict__ occP, float* __restrict__ sumocc) {
  __shared__ short smem[24576];  // 48KB: buf0(16K) | buf1(16K) | h2s(16K)
  short* const buf0 = smem;           // 8192 shorts
  short* const buf1 = smem + 8192;    // 8192 shorts
  short* const h1s = smem;            // 32KB planar [c4chunk][s] (aliases bufs)
  short* const h2s = smem + 16384;    // 16KB planar [c8chunk][s]
  const int tile = blockIdx.x, b = blockIdx.y;
  const int t = threadIdx.x, lane = t & 63, wv = t >> 6;
  const int q = lane >> 4, li = lane & 15;
  const int mh = (wv & 1) * 64, nh = (wv >> 1) * 64;
  const short* xTb = xTs + (size_t)(b * 128 + tile) * 65536;
  const f4_t fz = {0.f, 0.f, 0.f, 0.f};

  // phase 1: h1 = relu(Wo1 @ x + b1o)  [c4=128 x s=128], K=512, pipelined
  f4_t hcc[4][4];
#pragma unroll
  for (int i = 0; i < 4; ++i)
#pragma unroll
    for (int j = 0; j < 4; ++j) hcc[i][j] = fz;

  stage16k(xTb, buf1, wv, lane);  // chunk0 -> buf1
  for (int i = 0; i < 8; ++i) {
    BAR_FENCE();  // A: prev chunk's buffer reads retired by all waves
    if (i < 7) {
      short* nb_ = (i & 1) ? buf1 : buf0;
      stage16k(xTb + (i + 1) * 8192, nb_, wv, lane);
      WAIT_VM4();  // my chunk-i 4 glds landed; chunk-i+1's stay in flight
    } else {
      WAIT_VM0();
    }
    BAR_FENCE();  // B: everyone's chunk-i staged data visible
    const short* xs = (i & 1) ? buf0 : buf1;
    const short* og = wo1 + i * 8192;  // swizzled wo1 chunk, L2-hot global
#pragma unroll
    for (int kk = 0; kk < 2; ++kk) {
      const int pl = (4 * kk + q) * 128;
      bf8_t a[4], bb[4];
#pragma unroll
      for (int ma = 0; ma < 4; ++ma)
        a[ma] = *(const bf8_t*)&og[(pl + mh + 16 * ma + li) * 8];
#pragma unroll
      for (int nb = 0; nb < 4; ++nb)
        bb[nb] = *(const bf8_t*)&xs[(pl + nh + 16 * nb + li) * 8];
#pragma unroll
      for (int ma = 0; ma < 4; ++ma)
#pragma unroll
        for (int nb = 0; nb < 4; ++nb)
          hcc[ma][nb] = MFMA(a[ma], bb[nb], hcc[ma][nb], 0, 0, 0);
    }
  }
  WAIT_LGKM0();
  BAR_FENCE();  // all buffer reads retired everywhere; h1s (aliases bufs) OK
  // bias+relu -> h1s planar [c4chunk][s]
#pragma unroll
  for (int ma = 0; ma < 4; ++ma) {
    const int c40 = mh + 16 * ma + 4 * q;
    f4_t bv = *(const f4_t*)(bo1 + c40);
#pragma unroll
    for (int nb = 0; nb < 4; ++nb) {
      const int sl = nh + 16 * nb + li;
      s4_t p;
#pragma unroll
      for (int r = 0; r < 4; ++r) p[r] = f2bf(fmaxf(hcc[ma][nb][r] + bv[r], 0.0f));
      *(s4_t*)&h1s[((c40 >> 3) * 128 + sl) * 8 + (c40 & 7)] = p;
    }
  }
  __syncthreads();
  // phase 2: h2 = relu(Wo2 @ h1 + b2o)  [c8=64 x s=128], K=c4=128
  f4_t a2[4][2];
#pragma unroll
  for (int i = 0; i < 4; ++i) { a2[i][0] = fz; a2[i][1] = fz; }
#pragma unroll
  for (int kk = 0; kk < 4; ++kk) {
    const int pl = (4 * kk + q) * 128;
    bf8_t a[4], bb[2];
#pragma unroll
    for (int ma = 0; ma < 4; ++ma)
      a[ma] = *(const bf8_t*)(wo2 + (size_t)(16 * ma + li) * 128 + kk * 32 + q * 8);
#pragma unroll
    for (int nb = 0; nb < 2; ++nb)
      bb[nb] = *(const bf8_t*)&h1s[(pl + 32 * wv + 16 * nb + li) * 8];
#pragma unroll
    for (int ma = 0; ma < 4; ++ma)
#pragma unroll
      for (int nb = 0; nb < 2; ++nb)
        a2[ma][nb] = MFMA(a[ma], bb[nb], a2[ma][nb], 0, 0, 0);
  }
  // h2 -> h2s planar [c8chunk][s]; disjoint from h1s, wave-private s rows
#pragma unroll
  for (int ma = 0; ma < 4; ++ma) {
    const int c80 = 16 * ma + 4 * q;
    f4_t bv = *(const f4_t*)(bo2 + c80);
#pragma unroll
    for (int nb = 0; nb < 2; ++nb) {
      const int sl = 32 * wv + 16 * nb + li;
      s4_t p;
#pragma unroll
      for (int r = 0; r < 4; ++r) p[r] = f2bf(fmaxf(a2[ma][nb][r] + bv[r], 0.0f));
      *(s4_t*)&h2s[((c80 >> 3) * 128 + sl) * 8 + (c80 & 7)] = p;
    }
  }
  // phase 3: occ = |Wo3 @ h2|  [o=64 x s=128], K=c8=64
  f4_t a3[4][2];
#pragma unroll
  for (int i = 0; i < 4; ++i) { a3[i][0] = fz; a3[i][1] = fz; }
#pragma unroll
  for (int kk = 0; kk < 2; ++kk) {
    const int pl = (4 * kk + q) * 128;
    bf8_t a[4], bb[2];
#pragma unroll
    for (int ma = 0; ma < 4; ++ma)
      a[ma] = *(const bf8_t*)(wo3 + (size_t)(16 * ma + li) * 64 + kk * 32 + q * 8);
#pragma unroll
    for (int nb = 0; nb < 2; ++nb)
      bb[nb] = *(const bf8_t*)&h2s[(pl + 32 * wv + 16 * nb + li) * 8];
#pragma unroll
    for (int ma = 0; ma < 4; ++ma)
#pragma unroll
      for (int nb = 0; nb < 2; ++nb)
        a3[ma][nb] = MFMA(a[ma], bb[nb], a3[ma][nb], 0, 0, 0);
  }
  // |.| -> occP planar tile [s8][o][s0]
  short* ot = occP + (size_t)(b * 128 + tile) * 8192;
#pragma unroll
  for (int ma = 0; ma < 4; ++ma)
#pragma unroll
    for (int nb = 0; nb < 2; ++nb) {
      const int o = 16 * ma + 4 * q;
      const int sl = 32 * wv + 16 * nb + li;
#pragma unroll
      for (int r = 0; r < 4; ++r)
        ot[(sl >> 3) * 512 + (o + r) * 8 + (sl & 7)] = f2bf(fabsf(a3[ma][nb][r]));
    }
  // sumocc[b][o] += sum_s |occ| (fp32)
#pragma unroll
  for (int ma = 0; ma < 4; ++ma)
#pragma unroll
    for (int r = 0; r < 4; ++r) {
      float v = fabsf(a3[ma][0][r]) + fabsf(a3[ma][1][r]);
#pragma unroll
      for (int m = 1; m < 16; m <<= 1) v += __shfl_xor(v, m, 64);
      if (li == 0) atomicAdd(&sumocc[b * 64 + 16 * ma + 4 * q + r], v);
    }
}

// ---------------- r1 GEMM + spatial contraction into M ----------------------
// 4 waves, 64KB LDS. K-loop stages x only; w1 B-frags direct from L2 global.
// r1s no longer aliases the staging buffers (one barrier saved per tile).
__global__ __launch_bounds__(256) void k_feat(
    const short* __restrict__ xTs, const short* __restrict__ w1s,
    const float* __restrict__ b1, const short* __restrict__ occP,
    float* __restrict__ M) {
  __shared__ short smem[32768];  // 64KB: r1s(32K) | buf0(16K) | buf1(16K)
  short* const r1s = smem;            // 16384 shorts, planar [schunk][j]
  short* const buf0 = smem + 16384;   // 8192 shorts
  short* const buf1 = smem + 24576;   // 8192 shorts
  const int sg = blockIdx.x, cb = blockIdx.y, b = blockIdx.z;
  const int t = threadIdx.x, lane = t & 63, wv = t >> 6;
  const int q = lane >> 4, li = lane & 15;
  const int mh = (wv & 1) * 64, nh = (wv >> 1) * 64;
  const short* w1b = w1s + (size_t)cb * 65536;  // [kc][k8][j][k0] for this jc
  const f4_t fz = {0.f, 0.f, 0.f, 0.f};

  float biasv[4];
#pragma unroll
  for (int nb = 0; nb < 4; ++nb) biasv[nb] = b1[cb * 128 + nh + 16 * nb + li];

  f4_t macc[4][2];
#pragma unroll
  for (int i = 0; i < 4; ++i) { macc[i][0] = fz; macc[i][1] = fz; }

  // prologue: tile0 chunk0 -> buf1
  stage16k(xTs + (size_t)(b * 128 + sg * 4) * 65536, buf1, wv, lane);

  for (int tt = 0; tt < 4; ++tt) {
    const int st = sg * 4 + tt;
    const short* xTb = xTs + (size_t)(b * 128 + st) * 65536;
    f4_t acc[4][4];
#pragma unroll
    for (int i = 0; i < 4; ++i)
#pragma unroll
      for (int j = 0; j < 4; ++j) acc[i][j] = fz;

    for (int i = 0; i < 8; ++i) {
      BAR_FENCE();  // A: prev chunk's buffer reads retired by all waves
      if (i < 7) {
        short* nb_ = (i & 1) ? buf1 : buf0;
        stage16k(xTb + (i + 1) * 8192, nb_, wv, lane);
        WAIT_VM4();  // chunk-i landed; chunk-i+1 stays in flight
      } else {
        WAIT_VM0();
      }
      BAR_FENCE();  // B: all waves' chunk-i visible
      const short* xs = (i & 1) ? buf0 : buf1;
      const short* wg = w1b + i * 8192;  // swizzled w1 chunk, L2-hot global
#pragma unroll
      for (int kk = 0; kk < 2; ++kk) {
        const int pl = (4 * kk + q) * 128;
        bf8_t a[4], bb[4];
#pragma unroll
        for (int ma = 0; ma < 4; ++ma)
          a[ma] = *(const bf8_t*)&xs[(pl + mh + 16 * ma + li) * 8];
#pragma unroll
        for (int nb = 0; nb < 4; ++nb)
          bb[nb] = *(const bf8_t*)&wg[(pl + nh + 16 * nb + li) * 8];
#pragma unroll
        for (int ma = 0; ma < 4; ++ma)
#pragma unroll
          for (int nb = 0; nb < 4; ++nb)
            acc[ma][nb] = MFMA(a[ma], bb[nb], acc[ma][nb], 0, 0, 0);
      }
    }
    // r1 = relu(acc + b1) -> r1s planar [schunk][j] (disjoint from bufs;
    // prev tile's contraction reads long retired by the 8 rounds above)
#pragma unroll
    for (int ma = 0; ma < 4; ++ma) {
      const int sl0 = mh + 16 * ma + 4 * q;  // 4 consecutive s
#pragma unroll
      for (int nb = 0; nb < 4; ++nb) {
        const int jl = nh + 16 * nb + li;
        s4_t p;
#pragma unroll
        for (int r = 0; r < 4; ++r)
          p[r] = f2bf(fmaxf(acc[ma][nb][r] + biasv[nb], 0.0f));
        *(s4_t*)&r1s[((sl0 >> 3) * 128 + jl) * 8 + (sl0 & 7)] = p;
      }
    }
    WAIT_LGKM0();
    BAR_FENCE();  // r1s visible to all waves
    // occ A-frags from global FIRST (older than prologue glds -> waits on
    // them leave the chunk0 prefetch in flight)
    const short* ot = occP + (size_t)(b * 128 + st) * 8192;
    bf8_t af[4][4];
#pragma unroll
    for (int kc = 0; kc < 4; ++kc)
#pragma unroll
      for (int ma = 0; ma < 4; ++ma)  // planar: 16 lanes read 256B contiguous
        af[kc][ma] = *(const bf8_t*)(ot + ((kc * 4 + q) * 64 + 16 * ma + li) * 8);
    // next tile's chunk0 prologue -> buf1 (chunk6 reads retired at i=7 A)
    if (tt < 3) stage16k(xTb + 65536, buf1, wv, lane);
    // M[o][j] += occ[o][s] * r1[j][s]  (K = s = 128)
#pragma unroll
    for (int kc = 0; kc < 4; ++kc) {
      const int pl = (4 * kc + q) * 128;
      bf8_t bb[2];
#pragma unroll
      for (int nb = 0; nb < 2; ++nb)
        bb[nb] = *(const bf8_t*)&r1s[(pl + 32 * wv + 16 * nb + li) * 8];
#pragma unroll
      for (int ma = 0; ma < 4; ++ma)
#pragma unroll
        for (int nb = 0; nb < 2; ++nb)
          macc[ma][nb] = MFMA(af[kc][ma], bb[nb], macc[ma][nb], 0, 0, 0);
    }
  }
  // flush partial M (64 x 128 per block) once
#pragma unroll
  for (int ma = 0; ma < 4; ++ma)
#pragma unroll
    for (int nb = 0; nb < 2; ++nb) {
      const int jg = cb * 128 + 32 * wv + 16 * nb + li;
#pragma unroll
      for (int r = 0; r < 4; ++r) {
        const int o = 16 * ma + 4 * q + r;
        atomicAdd(&M[((size_t)b * 64 + o) * 512 + jg], macc[ma][nb][r]);
      }
    }
}

// ---------------- epilogue: out = (M @ W2^T + sumocc * b2^T) / S ------------
__global__ __launch_bounds__(256) void k_out(
    const float* __restrict__ M, const float* __restrict__ sumocc,
    const float* __restrict__ w2, const float* __restrict__ b2,
    float* __restrict__ out) {
  __shared__ float Mlds[16][516];
  __shared__ float Wlds[16][516];
  const int cg = blockIdx.x, og = blockIdx.y, b = blockIdx.z;
  const int t = threadIdx.x;
  const float* Msrc = M + ((size_t)b * 64 + og * 16) * 512;
  const float* Wsrc = w2 + (size_t)cg * 16 * 512;
#pragma unroll
  for (int k = 0; k < 8; ++k) {
    const int fi = k * 256 + t;              // f4 index 0..2047
    const int row = fi >> 7, col = (fi & 127) * 4;
    *(f4_t*)&Mlds[row][col] = *(const f4_t*)(Msrc + row * 512 + col);
    *(f4_t*)&Wlds[row][col] = *(const f4_t*)(Wsrc + row * 512 + col);
  }
  __syncthreads();
  const int o = t >> 4, c = t & 15;
  float s0 = 0.f, s1 = 0.f;
#pragma unroll 8
  for (int j = 0; j < 512; j += 8) {
    f4_t m0 = *(const f4_t*)&Mlds[o][j];
    f4_t w0 = *(const f4_t*)&Wlds[c][j];
    f4_t m1 = *(const f4_t*)&Mlds[o][j + 4];
    f4_t w1 = *(const f4_t*)&Wlds[c][j + 4];
    s0 += m0[0] * w0[0] + m0[1] * w0[1] + m0[2] * w0[2] + m0[3] * w0[3];
    s1 += m1[0] * w1[0] + m1[1] * w1[1] + m1[2] * w1[2] + m1[3] * w1[3];
  }
  const int og_ = og * 16 + o, cg_ = cg * 16 + c;
  out[((size_t)b * 64 + og_) * 512 + cg_] =
      ((s0 + s1) + sumocc[b * 64 + og_] * b2[cg_]) * (1.0f / 16384.0f);
}

// ---------------- launch ----------------------------------------------------
// ws layout (bytes):
//   0         xTs     4*16384*512 bf16 = 67108864   (swizzled tiles)
//   67108864  wb      339968 bf16 (w1s | wo1s | wo2 | wo3) = 679936
//   67788800  occP    4*64*16384 bf16  = 8388608    (planar tiles)
//   76177408  M       4*64*512 fp32    = 524288
//   76701696  sumocc  256 fp32         = 1024
extern "C" void kernel_launch(void* const* d_in, const int* in_sizes, int n_in,
                              void* d_out, int out_size, void* d_ws, size_t ws_size,
                              hipStream_t stream) {
  (void)in_sizes; (void)n_in; (void)out_size; (void)ws_size;
  const float* x      = (const float*)d_in[0];
  const float* w_add1 = (const float*)d_in[1];
  const float* b_add1 = (const float*)d_in[2];
  const float* w_add2 = (const float*)d_in[3];
  const float* b_add2 = (const float*)d_in[4];
  const float* w_occ1 = (const float*)d_in[5];
  const float* b_occ1 = (const float*)d_in[6];
  const float* w_occ2 = (const float*)d_in[7];
  const float* b_occ2 = (const float*)d_in[8];
  const float* w_occ3 = (const float*)d_in[9];

  char* ws = (char*)d_ws;
  short* xTs     = (short*)(ws);
  short* wb      = (short*)(ws + 67108864);
  short* occP    = (short*)(ws + 67788800);
  float* M       = (float*)(ws + 76177408);
  float* sumocc  = (float*)(ws + 76701696);

  hipMemsetAsync(M, 0, 524288 + 1024, stream);  // M + sumocc
  k_transpose<<<dim3(128, 8, 4), dim3(256), 0, stream>>>(
      x, xTs, w_add1, w_occ1, w_occ2, w_occ3, wb);

  const short* w1sp = wb;
  const short* wbo1 = wb + 262144;
  const short* wbo2 = wb + 327680;
  const short* wbo3 = wb + 335872;
  k_occ<<<dim3(128, 4), dim3(256), 0, stream>>>(xTs, wbo1, wbo2, wbo3,
                                                b_occ1, b_occ2, occP, sumocc);
  k_feat<<<dim3(32, 4, 4), dim3(256), 0, stream>>>(xTs, w1sp, b_add1, occP, M);
  k_out<<<dim3(32, 4, 4), dim3(256), 0, stream>>>(M, sumocc, w_add2, b_add2,
                                                  (float*)d_out);
}

// Round 10
// 350.780 us; speedup vs baseline: 1.2399x; 1.0914x over previous
//
#include <hip/hip_runtime.h>

// OccurrencePool R12: k_transpose + k_occ fused into k_toc.
// Evidence trail: k_occ stuck at 94-99us across counted-vmcnt (R7), TLP
// x2 (R10b: worse), hybrid sourcing / +1 block/CU (R11: neutral) -> its
// floor is structural: it re-reads from global the 64MB xTs that
// k_transpose just built. k_toc does, per 64-channel chunk: coalesced fp32
// x load -> LDS transpose/convert -> bf16 chunk consumed IMMEDIATELY by the
// Wo1 MFMA phase (wo1 frags direct from L2-hot global, R11-proven neutral)
// AND written to xTs global for k_feat (which reads each tile 4x across cb
// and keeps its proven staged structure). occ's xTs round-trip + one
// dispatch gap deleted. LDS 49.4KB (tls|xchunk, h1s/h2s alias) = 3 bl/CU.
// Weight convert back to a tiny standalone k_convert (k_toc consumes wo1).
// k_feat / k_out: byte-identical to R9 (best, 376us).
//   r1  = relu(W1 x + b1)                          (bf16 MFMA, 34.4 GF)
//   occ = |W3 relu(W2o relu(W1o x + b1o) + b2o)|   (bf16 MFMA, 10.2 GF)
//   M[b,o,j]   = sum_s occ[b,o,s] r1[b,j,s]        (bf16 MFMA, 4.3 GF)
//   out[b,o,c] = (sum_j M[o,j] W2[c,j] + b2[c]*sumocc[b,o]) / S
// Tile layout (per 128-voxel tile, per 64-wide K chunk kc):
//   linear = kc*8192 + k8*1024 + row*8 + k0   (shorts; k8=(k>>3)&7, k0=k&7)

#define S_TOT 16384  // T*H*W per batch

typedef __attribute__((ext_vector_type(8))) short bf8_t;  // 8 bf16 (4 VGPRs)
typedef __attribute__((ext_vector_type(4))) short s4_t;   // 4 bf16
typedef __attribute__((ext_vector_type(4))) float f4_t;

#define MFMA __builtin_amdgcn_mfma_f32_16x16x32_bf16

// raw barrier + code-motion fence (k_feat's counted-vmcnt pipeline)
#define BAR_FENCE() do { __builtin_amdgcn_s_barrier(); \
                         asm volatile("" ::: "memory"); } while (0)
#define WAIT_VM8()  asm volatile("s_waitcnt vmcnt(8)" ::: "memory")
#define WAIT_VM0()  asm volatile("s_waitcnt vmcnt(0)" ::: "memory")
#define WAIT_LGKM0() asm volatile("s_waitcnt lgkmcnt(0)" ::: "memory")

__device__ __forceinline__ short f2bf(float f) {
  union { float f; unsigned u; } v; v.f = f;
  unsigned u = v.u + 0x7FFFu + ((v.u >> 16) & 1u);  // RNE
  return (short)(u >> 16);
}

__device__ __forceinline__ void glds16(const void* g, void* l) {
  __builtin_amdgcn_global_load_lds(
      (const __attribute__((address_space(1))) void*)g,
      (__attribute__((address_space(3))) void*)l, 16, 0, 0);
}

// Contiguous 16KB global -> LDS copy (4 waves): 4 glds/wave, each
// lane-contiguous 1KB: g + off + lane*8 shorts; HW adds lane*16B on LDS side.
__device__ __forceinline__ void stage16k(const short* g, short* lds,
                                         int wv, int lane) {
#pragma unroll
  for (int i = 0; i < 4; ++i) {
    const int off = (wv * 4 + i) * 512;
    glds16(g + off + lane * 8, lds + off);
  }
}

// ---------------- weights fp32 -> bf16, w1/wo1 pre-swizzled -----------------
__global__ __launch_bounds__(256) void k_convert(
    const float* __restrict__ w1, const float* __restrict__ wo1,
    const float* __restrict__ wo2, const float* __restrict__ wo3,
    short* __restrict__ dst) {
  int i = blockIdx.x * 256 + threadIdx.x;
  if (i < 262144) {  // w1[j][k] -> [jc][kc][k8][j&127][k0]
    const int j = i >> 9, k = i & 511;
    const int di = ((j >> 7) * 8 + (k >> 6)) * 8192 + ((k >> 3) & 7) * 1024 +
                   (j & 127) * 8 + (k & 7);
    dst[di] = f2bf(w1[i]);
  } else if (i < 327680) {  // wo1[c4][k] -> [kc][k8][c4][k0]
    const int e = i - 262144;
    const int c4 = e >> 9, k = e & 511;
    const int di = 262144 + (k >> 6) * 8192 + ((k >> 3) & 7) * 1024 +
                   c4 * 8 + (k & 7);
    dst[di] = f2bf(wo1[e]);
  } else if (i < 335872) {
    dst[i] = f2bf(wo2[i - 327680]);
  } else if (i < 339968) {
    dst[i] = f2bf(wo3[i - 335872]);
  }
}

// ------------- fused transpose + occ chain: one block per s-tile ------------
// Per chunk i (64 channels): fp32 x -> tls -> bf16 xchunk (LDS) + xTs
// (global, for k_feat); MFMA consumes xchunk immediately (wo1 from global).
__global__ __launch_bounds__(256) void k_toc(
    const float* __restrict__ x, short* __restrict__ xTs,
    const short* __restrict__ wo1, const short* __restrict__ wo2,
    const short* __restrict__ wo3, const float* __restrict__ bo1,
    const float* __restrict__ bo2,
    short* __restrict__ occP, float* __restrict__ sumocc) {
  __shared__ __align__(16) char smem_raw[49408];  // tls 33024B | xchunk 16384B
  float (*tls)[129] = (float (*)[129])smem_raw;   // [c 64][s 128+pad]
  short* const xchunk = (short*)(smem_raw + 33024);  // 8192 shorts, one chunk
  short* const h1s = (short*)smem_raw;               // 32KB planar, after loop
  short* const h2s = xchunk;                         // 16KB planar
  const int tile = blockIdx.x, b = blockIdx.y;
  const int t = threadIdx.x, lane = t & 63, wv = t >> 6;
  const int q = lane >> 4, li = lane & 15;
  const int mh = (wv & 1) * 64, nh = (wv >> 1) * 64;
  const f4_t fz = {0.f, 0.f, 0.f, 0.f};

  const int cr = t >> 2, ss = (t & 3) * 32;  // fp32 load role
  const float* xb = x + ((size_t)b * 512 + cr) * S_TOT + tile * 128 + ss;

  f4_t hcc[4][4];
#pragma unroll
  for (int i = 0; i < 4; ++i)
#pragma unroll
    for (int j = 0; j < 4; ++j) hcc[i][j] = fz;

  f4_t xr[8];
#pragma unroll
  for (int k = 0; k < 8; ++k) xr[k] = *(const f4_t*)(xb + k * 4);  // chunk 0

  for (int i = 0; i < 8; ++i) {
    // tls free (first iter trivially; else everyone passed prev B2)
#pragma unroll
    for (int k = 0; k < 8; ++k) {
      f4_t v = xr[k];
#pragma unroll
      for (int j = 0; j < 4; ++j) tls[cr][ss + k * 4 + j] = v[j];
    }
    __syncthreads();  // B1: tls populated
    if (i < 7) {      // issue next chunk's loads; land under produce phase
      const float* nsrc = xb + (size_t)(i + 1) * 64 * S_TOT;
#pragma unroll
      for (int k = 0; k < 8; ++k) xr[k] = *(const f4_t*)(nsrc + k * 4);
    }
    // produce bf16 chunk: 512 items, 2/thread -> xchunk LDS + xTs global
#pragma unroll
    for (int h = 0; h < 2; ++h) {
      const int id = h * 256 + t;
      const int s_in = id >> 2, cs = (id & 3) * 16, k8 = cs >> 3;
      alignas(16) short tmp[16];
#pragma unroll
      for (int j = 0; j < 16; ++j) tmp[j] = f2bf(tls[cs + j][s_in]);
      short* lb = xchunk + k8 * 1024 + s_in * 8;
      *(bf8_t*)lb          = *(const bf8_t*)&tmp[0];
      *(bf8_t*)(lb + 1024) = *(const bf8_t*)&tmp[8];
      short* gb = xTs + (((size_t)(b * 128 + tile) * 8 + i) * 8 + k8) * 1024 +
                  s_in * 8;
      *(bf8_t*)gb          = *(const bf8_t*)&tmp[0];
      *(bf8_t*)(gb + 1024) = *(const bf8_t*)&tmp[8];
    }
    __syncthreads();  // B2: xchunk visible; tls reads retired
    // MFMA: hcc += wo1_chunk(global frags) @ xchunk
    const short* og = wo1 + i * 8192;
#pragma unroll
    for (int kk = 0; kk < 2; ++kk) {
      const int pl = (4 * kk + q) * 128;
      bf8_t a[4], bb[4];
#pragma unroll
      for (int ma = 0; ma < 4; ++ma)
        a[ma] = *(const bf8_t*)&og[(pl + mh + 16 * ma + li) * 8];
#pragma unroll
      for (int nb = 0; nb < 4; ++nb)
        bb[nb] = *(const bf8_t*)&xchunk[(pl + nh + 16 * nb + li) * 8];
#pragma unroll
      for (int ma = 0; ma < 4; ++ma)
#pragma unroll
        for (int nb = 0; nb < 4; ++nb)
          hcc[ma][nb] = MFMA(a[ma], bb[nb], hcc[ma][nb], 0, 0, 0);
    }
    // next iter's tls writes race nothing: xchunk reads fenced by next B1.
  }
  __syncthreads();  // all xchunk reads retired; tls region free -> h1s
  // bias+relu -> h1s planar [c4chunk][s]
#pragma unroll
  for (int ma = 0; ma < 4; ++ma) {
    const int c40 = mh + 16 * ma + 4 * q;
    f4_t bv = *(const f4_t*)(bo1 + c40);
#pragma unroll
    for (int nb = 0; nb < 4; ++nb) {
      const int sl = nh + 16 * nb + li;
      s4_t p;
#pragma unroll
      for (int r = 0; r < 4; ++r) p[r] = f2bf(fmaxf(hcc[ma][nb][r] + bv[r], 0.0f));
      *(s4_t*)&h1s[((c40 >> 3) * 128 + sl) * 8 + (c40 & 7)] = p;
    }
  }
  __syncthreads();  // h1s visible (also: xchunk region now reusable as h2s)
  // phase 2: h2 = relu(Wo2 @ h1 + b2o)  [c8=64 x s=128], K=c4=128
  f4_t a2[4][2];
#pragma unroll
  for (int i = 0; i < 4; ++i) { a2[i][0] = fz; a2[i][1] = fz; }
#pragma unroll
  for (int kk = 0; kk < 4; ++kk) {
    const int pl = (4 * kk + q) * 128;
    bf8_t a[4], bb[2];
#pragma unroll
    for (int ma = 0; ma < 4; ++ma)
      a[ma] = *(const bf8_t*)(wo2 + (size_t)(16 * ma + li) * 128 + kk * 32 + q * 8);
#pragma unroll
    for (int nb = 0; nb < 2; ++nb)
      bb[nb] = *(const bf8_t*)&h1s[(pl + 32 * wv + 16 * nb + li) * 8];
#pragma unroll
    for (int ma = 0; ma < 4; ++ma)
#pragma unroll
      for (int nb = 0; nb < 2; ++nb)
        a2[ma][nb] = MFMA(a[ma], bb[nb], a2[ma][nb], 0, 0, 0);
  }
  // h2 -> h2s planar [c8chunk][s]; wave-private s rows (no barrier)
#pragma unroll
  for (int ma = 0; ma < 4; ++ma) {
    const int c80 = 16 * ma + 4 * q;
    f4_t bv = *(const f4_t*)(bo2 + c80);
#pragma unroll
    for (int nb = 0; nb < 2; ++nb) {
      const int sl = 32 * wv + 16 * nb + li;
      s4_t p;
#pragma unroll
      for (int r = 0; r < 4; ++r) p[r] = f2bf(fmaxf(a2[ma][nb][r] + bv[r], 0.0f));
      *(s4_t*)&h2s[((c80 >> 3) * 128 + sl) * 8 + (c80 & 7)] = p;
    }
  }
  // phase 3: occ = |Wo3 @ h2|  [o=64 x s=128], K=c8=64
  f4_t a3[4][2];
#pragma unroll
  for (int i = 0; i < 4; ++i) { a3[i][0] = fz; a3[i][1] = fz; }
#pragma unroll
  for (int kk = 0; kk < 2; ++kk) {
    const int pl = (4 * kk + q) * 128;
    bf8_t a[4], bb[2];
#pragma unroll
    for (int ma = 0; ma < 4; ++ma)
      a[ma] = *(const bf8_t*)(wo3 + (size_t)(16 * ma + li) * 64 + kk * 32 + q * 8);
#pragma unroll
    for (int nb = 0; nb < 2; ++nb)
      bb[nb] = *(const bf8_t*)&h2s[(pl + 32 * wv + 16 * nb + li) * 8];
#pragma unroll
    for (int ma = 0; ma < 4; ++ma)
#pragma unroll
      for (int nb = 0; nb < 2; ++nb)
        a3[ma][nb] = MFMA(a[ma], bb[nb], a3[ma][nb], 0, 0, 0);
  }
  // |.| -> occP planar tile [s8][o][s0]
  short* ot = occP + (size_t)(b * 128 + tile) * 8192;
#pragma unroll
  for (int ma = 0; ma < 4; ++ma)
#pragma unroll
    for (int nb = 0; nb < 2; ++nb) {
      const int o = 16 * ma + 4 * q;
      const int sl = 32 * wv + 16 * nb + li;
#pragma unroll
      for (int r = 0; r < 4; ++r)
        ot[(sl >> 3) * 512 + (o + r) * 8 + (sl & 7)] = f2bf(fabsf(a3[ma][nb][r]));
    }
  // sumocc[b][o] += sum_s |occ| (fp32)
#pragma unroll
  for (int ma = 0; ma < 4; ++ma)
#pragma unroll
    for (int r = 0; r < 4; ++r) {
      float v = fabsf(a3[ma][0][r]) + fabsf(a3[ma][1][r]);
#pragma unroll
      for (int m = 1; m < 16; m <<= 1) v += __shfl_xor(v, m, 64);
      if (li == 0) atomicAdd(&sumocc[b * 64 + 16 * ma + 4 * q + r], v);
    }
}

// ---------------- r1 GEMM + spatial contraction into M (R9 verbatim) --------
__global__ __launch_bounds__(256) void k_feat(
    const short* __restrict__ xTs, const short* __restrict__ w1s,
    const float* __restrict__ b1, const short* __restrict__ occP,
    float* __restrict__ M) {
  __shared__ short smem[32768];  // 64KB: buf0 | buf1
  short* const buf0 = smem;
  short* const buf1 = smem + 16384;
  short* const r1s = buf0;  // 32KB planar [schunk][j] after each K-loop
  const int sg = blockIdx.x, cb = blockIdx.y, b = blockIdx.z;
  const int t = threadIdx.x, lane = t & 63, wv = t >> 6;
  const int q = lane >> 4, li = lane & 15;
  const int mh = (wv & 1) * 64, nh = (wv >> 1) * 64;
  const short* w1b = w1s + (size_t)cb * 65536;  // [kc][k8][j][k0] for this jc
  const f4_t fz = {0.f, 0.f, 0.f, 0.f};

  float biasv[4];
#pragma unroll
  for (int nb = 0; nb < 4; ++nb) biasv[nb] = b1[cb * 128 + nh + 16 * nb + li];

  f4_t macc[4][2];
#pragma unroll
  for (int i = 0; i < 4; ++i) { macc[i][0] = fz; macc[i][1] = fz; }

  // prologue: tile0 chunk0 -> buf1
  {
    const short* xT0 = xTs + (size_t)(b * 128 + sg * 4) * 65536;
    stage16k(xT0, buf1, wv, lane);
    stage16k(w1b, buf1 + 8192, wv, lane);
  }

  for (int tt = 0; tt < 4; ++tt) {
    const int st = sg * 4 + tt;
    const short* xTb = xTs + (size_t)(b * 128 + st) * 65536;
    f4_t acc[4][4];
#pragma unroll
    for (int i = 0; i < 4; ++i)
#pragma unroll
      for (int j = 0; j < 4; ++j) acc[i][j] = fz;

    for (int i = 0; i < 8; ++i) {
      BAR_FENCE();  // A: prev chunk's (and prev contraction's) LDS reads done
      if (i < 7) {
        short* nb_ = (i & 1) ? buf1 : buf0;
        stage16k(xTb + (i + 1) * 8192, nb_, wv, lane);
        stage16k(w1b + (i + 1) * 8192, nb_ + 8192, wv, lane);
        WAIT_VM8();  // chunk-i landed; chunk-i+1 stays in flight
      } else {
        WAIT_VM0();
      }
      BAR_FENCE();  // B: all waves' chunk-i visible
      const short* xs = (i & 1) ? buf0 : buf1;
      const short* wsp = xs + 8192;
#pragma unroll
      for (int kk = 0; kk < 2; ++kk) {
        const int pl = (4 * kk + q) * 128;
        bf8_t a[4], bb[4];
#pragma unroll
        for (int ma = 0; ma < 4; ++ma)
          a[ma] = *(const bf8_t*)&xs[(pl + mh + 16 * ma + li) * 8];
#pragma unroll
        for (int nb = 0; nb < 4; ++nb)
          bb[nb] = *(const bf8_t*)&wsp[(pl + nh + 16 * nb + li) * 8];
#pragma unroll
        for (int ma = 0; ma < 4; ++ma)
#pragma unroll
          for (int nb = 0; nb < 4; ++nb)
            acc[ma][nb] = MFMA(a[ma], bb[nb], acc[ma][nb], 0, 0, 0);
      }
    }
    WAIT_LGKM0();
    BAR_FENCE();  // chunk7 (buf0) reads retired everywhere; buf0 reusable
    // r1 = relu(acc + b1) -> r1s planar [schunk][j] (buf0)
#pragma unroll
    for (int ma = 0; ma < 4; ++ma) {
      const int sl0 = mh + 16 * ma + 4 * q;  // 4 consecutive s
#pragma unroll
      for (int nb = 0; nb < 4; ++nb) {
        const int jl = nh + 16 * nb + li;
        s4_t p;
#pragma unroll
        for (int r = 0; r < 4; ++r)
          p[r] = f2bf(fmaxf(acc[ma][nb][r] + biasv[nb], 0.0f));
        *(s4_t*)&r1s[((sl0 >> 3) * 128 + jl) * 8 + (sl0 & 7)] = p;
      }
    }
    WAIT_LGKM0();
    BAR_FENCE();  // r1s visible to all waves
    // occ A-frags from global FIRST (older than prologue glds)
    const short* ot = occP + (size_t)(b * 128 + st) * 8192;
    bf8_t af[4][4];
#pragma unroll
    for (int kc = 0; kc < 4; ++kc)
#pragma unroll
      for (int ma = 0; ma < 4; ++ma)  // planar: 16 lanes read 256B contiguous
        af[kc][ma] = *(const bf8_t*)(ot + ((kc * 4 + q) * 64 + 16 * ma + li) * 8);
    // next tile's chunk0 prologue -> buf1 (chunk6 reads retired at i=7 A)
    if (tt < 3) {
      stage16k(xTb + 65536, buf1, wv, lane);
      stage16k(w1b, buf1 + 8192, wv, lane);
    }
    // M[o][j] += occ[o][s] * r1[j][s]  (K = s = 128)
#pragma unroll
    for (int kc = 0; kc < 4; ++kc) {
      const int pl = (4 * kc + q) * 128;
      bf8_t bb[2];
#pragma unroll
      for (int nb = 0; nb < 2; ++nb)
        bb[nb] = *(const bf8_t*)&r1s[(pl + 32 * wv + 16 * nb + li) * 8];
#pragma unroll
      for (int ma = 0; ma < 4; ++ma)
#pragma unroll
        for (int nb = 0; nb < 2; ++nb)
          macc[ma][nb] = MFMA(af[kc][ma], bb[nb], macc[ma][nb], 0, 0, 0);
    }
  }
  // flush partial M (64 x 128 per block) once
#pragma unroll
  for (int ma = 0; ma < 4; ++ma)
#pragma unroll
    for (int nb = 0; nb < 2; ++nb) {
      const int jg = cb * 128 + 32 * wv + 16 * nb + li;
#pragma unroll
      for (int r = 0; r < 4; ++r) {
        const int o = 16 * ma + 4 * q + r;
        atomicAdd(&M[((size_t)b * 64 + o) * 512 + jg], macc[ma][nb][r]);
      }
    }
}

// ---------------- epilogue: out = (M @ W2^T + sumocc * b2^T) / S ------------
__global__ __launch_bounds__(256) void k_out(
    const float* __restrict__ M, const float* __restrict__ sumocc,
    const float* __restrict__ w2, const float* __restrict__ b2,
    float* __restrict__ out) {
  __shared__ float Mlds[16][516];
  __shared__ float Wlds[16][516];
  const int cg = blockIdx.x, og = blockIdx.y, b = blockIdx.z;
  const int t = threadIdx.x;
  const float* Msrc = M + ((size_t)b * 64 + og * 16) * 512;
  const float* Wsrc = w2 + (size_t)cg * 16 * 512;
#pragma unroll
  for (int k = 0; k < 8; ++k) {
    const int fi = k * 256 + t;              // f4 index 0..2047
    const int row = fi >> 7, col = (fi & 127) * 4;
    *(f4_t*)&Mlds[row][col] = *(const f4_t*)(Msrc + row * 512 + col);
    *(f4_t*)&Wlds[row][col] = *(const f4_t*)(Wsrc + row * 512 + col);
  }
  __syncthreads();
  const int o = t >> 4, c = t & 15;
  float s0 = 0.f, s1 = 0.f;
#pragma unroll 8
  for (int j = 0; j < 512; j += 8) {
    f4_t m0 = *(const f4_t*)&Mlds[o][j];
    f4_t w0 = *(const f4_t*)&Wlds[c][j];
    f4_t m1 = *(const f4_t*)&Mlds[o][j + 4];
    f4_t w1 = *(const f4_t*)&Wlds[c][j + 4];
    s0 += m0[0] * w0[0] + m0[1] * w0[1] + m0[2] * w0[2] + m0[3] * w0[3];
    s1 += m1[0] * w1[0] + m1[1] * w1[1] + m1[2] * w1[2] + m1[3] * w1[3];
  }
  const int og_ = og * 16 + o, cg_ = cg * 16 + c;
  out[((size_t)b * 64 + og_) * 512 + cg_] =
      ((s0 + s1) + sumocc[b * 64 + og_] * b2[cg_]) * (1.0f / 16384.0f);
}

// ---------------- launch ----------------------------------------------------
// ws layout (bytes):
//   0         xTs     4*16384*512 bf16 = 67108864   (swizzled tiles)
//   67108864  wb      339968 bf16 (w1s | wo1s | wo2 | wo3) = 679936
//   67788800  occP    4*64*16384 bf16  = 8388608    (planar tiles)
//   76177408  M       4*64*512 fp32    = 524288
//   76701696  sumocc  256 fp32         = 1024
extern "C" void kernel_launch(void* const* d_in, const int* in_sizes, int n_in,
                              void* d_out, int out_size, void* d_ws, size_t ws_size,
                              hipStream_t stream) {
  (void)in_sizes; (void)n_in; (void)out_size; (void)ws_size;
  const float* x      = (const float*)d_in[0];
  const float* w_add1 = (const float*)d_in[1];
  const float* b_add1 = (const float*)d_in[2];
  const float* w_add2 = (const float*)d_in[3];
  const float* b_add2 = (const float*)d_in[4];
  const float* w_occ1 = (const float*)d_in[5];
  const float* b_occ1 = (const float*)d_in[6];
  const float* w_occ2 = (const float*)d_in[7];
  const float* b_occ2 = (const float*)d_in[8];
  const float* w_occ3 = (const float*)d_in[9];

  char* ws = (char*)d_ws;
  short* xTs     = (short*)(ws);
  short* wb      = (short*)(ws + 67108864);
  short* occP    = (short*)(ws + 67788800);
  float* M       = (float*)(ws + 76177408);
  float* sumocc  = (float*)(ws + 76701696);

  hipMemsetAsync(M, 0, 524288 + 1024, stream);  // M + sumocc
  k_convert<<<dim3(1328), dim3(256), 0, stream>>>(w_add1, w_occ1, w_occ2, w_occ3, wb);

  const short* w1sp = wb;
  const short* wbo1 = wb + 262144;
  const short* wbo2 = wb + 327680;
  const short* wbo3 = wb + 335872;
  k_toc<<<dim3(128, 4), dim3(256), 0, stream>>>(
      x, xTs, wbo1, wbo2, wbo3, b_occ1, b_occ2, occP, sumocc);
  k_feat<<<dim3(32, 4, 4), dim3(256), 0, stream>>>(xTs, w1sp, b_add1, occP, M);
  k_out<<<dim3(32, 4, 4), dim3(256), 0, stream>>>(M, sumocc, w_add2, b_add2,
                                                  (float*)d_out);
}